// Round 3
// baseline (260.315 us; speedup 1.0000x reference)
//
#include <hip/hip_runtime.h>
#include <hip/hip_bf16.h>
#include <math.h>

// Problem constants (fixed by the reference)
#define NB 8
#define NC 9               // channels (== NUM_CLASSES)
#define PIXELS (768*768)   // 589824 pixels per batch image
#define BLOCK 256
#define PPT 24                         // pixels per thread (6 x int4)
#define CHUNK_PX (BLOCK * PPT)         // 6144
#define NCHUNK (PIXELS / CHUNK_PX)     // 96 exactly
#define NITER (PPT / 4)                // 6 vector iterations
#define NWAVE (BLOCK / 64)

// ws layout: sums[NB][8][NC] floats (576), then counts[NB][8] floats (64)
#define SUMS_ELEMS (NB * 8 * NC)
#define WS_FLOATS (SUMS_ELEMS + NB * 8)

__global__ __launch_bounds__(BLOCK)
void accum_kernel(const int* __restrict__ masks,
                  const float* __restrict__ outputs,
                  float* __restrict__ sums,    // [NB][8][NC]
                  float* __restrict__ counts)  // [NB][8]
{
    int blk = blockIdx.x;
    int chunk = blk % NCHUNK;
    int b = blk / NCHUNK;
    int t = threadIdx.x;
    int wave = t >> 6;
    int lane = t & 63;

    // ---- load mask chunk ONCE into registers (reused for all 9 channels) ----
    const int4* __restrict__ m4 =
        (const int4*)(masks + (size_t)b * PIXELS + (size_t)chunk * CHUNK_PX);
    int4 m[NITER];
    #pragma unroll
    for (int i = 0; i < NITER; ++i) m[i] = m4[t + i * BLOCK];

    __shared__ float red[NC][NWAVE][8];   // per-channel per-wave class sums
    __shared__ float red_c[NWAVE][8];     // per-wave class counts

    // ---- counts via ballot: one v_cmp per (component, class), scalar popcount ----
    {
        int cnt[8];
        #pragma unroll
        for (int k = 0; k < 8; ++k) cnt[k] = 0;
        #pragma unroll
        for (int i = 0; i < NITER; ++i) {
            #pragma unroll
            for (int k = 1; k <= 8; ++k) {
                cnt[k - 1] += __popcll(__ballot(m[i].x == k));
                cnt[k - 1] += __popcll(__ballot(m[i].y == k));
                cnt[k - 1] += __popcll(__ballot(m[i].z == k));
                cnt[k - 1] += __popcll(__ballot(m[i].w == k));
            }
        }
        if (lane == 0) {
            #pragma unroll
            for (int k = 0; k < 8; ++k) red_c[wave][k] = (float)cnt[k];
        }
    }

    // ---- per-channel accumulation with explicit next-channel prefetch ----
    const float* outbase = outputs + (size_t)b * NC * PIXELS + (size_t)chunk * CHUNK_PX;

    float4 buf[NITER];
    {
        const float4* o4 = (const float4*)(outbase);
        #pragma unroll
        for (int i = 0; i < NITER; ++i) buf[i] = o4[t + i * BLOCK];
    }

    const int p = lane & 1;
    const int q = (lane >> 1) & 1;
    const int r = (lane >> 2) & 1;

    #pragma unroll
    for (int c = 0; c < NC; ++c) {
        float4 nxt[NITER];
        if (c < NC - 1) {
            const float4* o4 = (const float4*)(outbase + (size_t)(c + 1) * PIXELS);
            #pragma unroll
            for (int i = 0; i < NITER; ++i) nxt[i] = o4[t + i * BLOCK];
        }

        float s[8];
        #pragma unroll
        for (int k = 0; k < 8; ++k) s[k] = 0.f;

        #pragma unroll
        for (int i = 0; i < NITER; ++i) {
            float4 v = buf[i];
            #pragma unroll
            for (int k = 1; k <= 8; ++k) {
                float a = s[k - 1];
                a += (m[i].x == k) ? v.x : 0.f;
                a += (m[i].y == k) ? v.y : 0.f;
                a += (m[i].z == k) ? v.z : 0.f;
                a += (m[i].w == k) ? v.w : 0.f;
                s[k - 1] = a;
            }
        }

        // ---- split-butterfly wave reduction: classes partitioned across lanes ----
        // Stage A (xor 1): even lanes keep classes 0-3, odd keep 4-7
        float u[4];
        #pragma unroll
        for (int j = 0; j < 4; ++j) {
            float x = p ? s[j] : s[j + 4];
            float y = __shfl_xor(x, 1, 64);
            u[j] = (p ? s[j + 4] : s[j]) + y;
        }
        // Stage B (xor 2)
        float v2[2];
        #pragma unroll
        for (int j = 0; j < 2; ++j) {
            float x = q ? u[j] : u[j + 2];
            float y = __shfl_xor(x, 2, 64);
            v2[j] = (q ? u[j + 2] : u[j]) + y;
        }
        // Stage C (xor 4)
        float w;
        {
            float x = r ? v2[0] : v2[1];
            float y = __shfl_xor(x, 4, 64);
            w = (r ? v2[1] : v2[0]) + y;
        }
        // Stages D-F: full-wave sum of each lane's class
        w += __shfl_xor(w, 8, 64);
        w += __shfl_xor(w, 16, 64);
        w += __shfl_xor(w, 32, 64);

        // lane 0..7 hold classes bit-reverse(lane&7): cls = 4p + 2q + r
        if (lane < 8) {
            int cls = (p << 2) | (q << 1) | r;
            red[c][wave][cls] = w;
        }

        #pragma unroll
        for (int i = 0; i < NITER; ++i) buf[i] = nxt[i];
    }

    __syncthreads();

    // ---- one atomic per (channel, class) pair; counts from 8 more threads ----
    if (t < NC * 8) {                 // t in [0,72): c = t>>3, k = t&7
        int c = t >> 3;
        int k = t & 7;
        float tot = 0.f;
        #pragma unroll
        for (int w = 0; w < NWAVE; ++w) tot += red[c][w][k];
        atomicAdd(&sums[(b * 8 + k) * NC + c], tot);
    } else if (t < NC * 8 + 8) {      // t in [72,80): class counts
        int k = t - NC * 8;
        float tot = 0.f;
        #pragma unroll
        for (int w = 0; w < NWAVE; ++w) tot += red_c[w][k];
        atomicAdd(&counts[b * 8 + k], tot);
    }
}

__global__ __launch_bounds__(64)
void finalize_kernel(const float* __restrict__ sums,
                     const float* __restrict__ counts,
                     float* __restrict__ out)
{
    int t = threadIdx.x;        // 0..63
    int b = t >> 3;             // batch
    int cls = t & 7;            // 0..7 -> class cls+1

    float cntv = counts[b * 8 + cls];
    float denom = fmaxf(cntv, 1.0f);

    float p[NC];
    float mx = -INFINITY;
    #pragma unroll
    for (int c = 0; c < NC; ++c) {
        p[c] = sums[(b * 8 + cls) * NC + c] / denom;
        mx = fmaxf(mx, p[c]);
    }
    float se = 0.f;
    #pragma unroll
    for (int c = 0; c < NC; ++c) se += expf(p[c] - mx);
    float lse = logf(se);

    float per = 0.f;
    #pragma unroll
    for (int c = 0; c < NC; ++c) {
        float tgt = (c == cls + 1) ? 0.9f : 0.0125f;
        per -= tgt * (p[c] - mx - lse);
    }

    bool present = cntv > 0.f;
    float val = present ? per : 0.f;
    float np  = present ? 1.f : 0.f;
    #pragma unroll
    for (int off = 32; off > 0; off >>= 1) {
        val += __shfl_down(val, off, 64);
        np  += __shfl_down(np,  off, 64);
    }
    if (t == 0) out[0] = val / fmaxf(np, 1.f);
}

extern "C" void kernel_launch(void* const* d_in, const int* in_sizes, int n_in,
                              void* d_out, int out_size, void* d_ws, size_t ws_size,
                              hipStream_t stream) {
    const int*   masks   = (const int*)d_in[0];
    const float* outputs = (const float*)d_in[1];
    float* sums   = (float*)d_ws;
    float* counts = sums + SUMS_ELEMS;

    // d_ws is poisoned with 0xAA before every call — zero the accumulators.
    hipMemsetAsync(d_ws, 0, WS_FLOATS * sizeof(float), stream);

    int grid = NB * NCHUNK;   // 768 blocks = exactly 3 per CU
    accum_kernel<<<grid, BLOCK, 0, stream>>>(masks, outputs, sums, counts);
    finalize_kernel<<<1, 64, 0, stream>>>(sums, counts, (float*)d_out);
}

// Round 4
// 258.506 us; speedup vs baseline: 1.0070x; 1.0070x over previous
//
#include <hip/hip_runtime.h>
#include <hip/hip_bf16.h>
#include <math.h>

// Problem constants (fixed by the reference)
#define NB 8
#define NC 9               // channels (== NUM_CLASSES)
#define PIXELS (768*768)   // 589824 pixels per batch image
#define BLOCK 256
#define PPT 12                         // pixels per thread (3 x int4) -> low VGPR
#define CHUNK_PX (BLOCK * PPT)         // 3072
#define NCHUNK (PIXELS / CHUNK_PX)     // 192 exactly
#define NITER (PPT / 4)                // 3 vector iterations
#define NWAVE (BLOCK / 64)
#define GRID (NB * NCHUNK)             // 1536 blocks = exactly 6 per CU
#define SLOT 80                        // per-block partial: 72 sums + 8 counts

__global__ __launch_bounds__(BLOCK)
void accum_kernel(const int* __restrict__ masks,
                  const float* __restrict__ outputs,
                  float* __restrict__ partial)   // [GRID][SLOT]
{
    int blk = blockIdx.x;
    int chunk = blk % NCHUNK;
    int b = blk / NCHUNK;
    int t = threadIdx.x;
    int wave = t >> 6;
    int lane = t & 63;

    // ---- load mask chunk ONCE into registers (reused for all 9 channels) ----
    const int4* __restrict__ m4 =
        (const int4*)(masks + (size_t)b * PIXELS + (size_t)chunk * CHUNK_PX);
    int4 m[NITER];
    #pragma unroll
    for (int i = 0; i < NITER; ++i) m[i] = m4[t + i * BLOCK];

    __shared__ float red[NC][NWAVE][8];   // per-channel per-wave class sums
    __shared__ float red_c[NWAVE][8];     // per-wave class counts

    // ---- counts via ballot: one v_cmp per (component, class), scalar popcount ----
    {
        int cnt[8];
        #pragma unroll
        for (int k = 0; k < 8; ++k) cnt[k] = 0;
        #pragma unroll
        for (int i = 0; i < NITER; ++i) {
            #pragma unroll
            for (int k = 1; k <= 8; ++k) {
                cnt[k - 1] += __popcll(__ballot(m[i].x == k));
                cnt[k - 1] += __popcll(__ballot(m[i].y == k));
                cnt[k - 1] += __popcll(__ballot(m[i].z == k));
                cnt[k - 1] += __popcll(__ballot(m[i].w == k));
            }
        }
        if (lane == 0) {
            #pragma unroll
            for (int k = 0; k < 8; ++k) red_c[wave][k] = (float)cnt[k];
        }
    }

    const float* outbase = outputs + (size_t)b * NC * PIXELS + (size_t)chunk * CHUNK_PX;

    const int p = lane & 1;
    const int q = (lane >> 1) & 1;
    const int r = (lane >> 2) & 1;

    // ---- per-channel accumulation; mask stays in registers ----
    #pragma unroll
    for (int c = 0; c < NC; ++c) {
        const float4* o4 = (const float4*)(outbase + (size_t)c * PIXELS);
        float4 buf[NITER];
        #pragma unroll
        for (int i = 0; i < NITER; ++i) buf[i] = o4[t + i * BLOCK];

        float s[8];
        #pragma unroll
        for (int k = 0; k < 8; ++k) s[k] = 0.f;

        #pragma unroll
        for (int i = 0; i < NITER; ++i) {
            float4 v = buf[i];
            #pragma unroll
            for (int k = 1; k <= 8; ++k) {
                float a = s[k - 1];
                a += (m[i].x == k) ? v.x : 0.f;
                a += (m[i].y == k) ? v.y : 0.f;
                a += (m[i].z == k) ? v.z : 0.f;
                a += (m[i].w == k) ? v.w : 0.f;
                s[k - 1] = a;
            }
        }

        // ---- split-butterfly wave reduction: classes partitioned across lanes ----
        float u[4];
        #pragma unroll
        for (int j = 0; j < 4; ++j) {
            float x = p ? s[j] : s[j + 4];
            float y = __shfl_xor(x, 1, 64);
            u[j] = (p ? s[j + 4] : s[j]) + y;
        }
        float v2[2];
        #pragma unroll
        for (int j = 0; j < 2; ++j) {
            float x = q ? u[j] : u[j + 2];
            float y = __shfl_xor(x, 2, 64);
            v2[j] = (q ? u[j + 2] : u[j]) + y;
        }
        float w;
        {
            float x = r ? v2[0] : v2[1];
            float y = __shfl_xor(x, 4, 64);
            w = (r ? v2[1] : v2[0]) + y;
        }
        w += __shfl_xor(w, 8, 64);
        w += __shfl_xor(w, 16, 64);
        w += __shfl_xor(w, 32, 64);

        if (lane < 8) {
            int cls = (p << 2) | (q << 1) | r;
            red[c][wave][cls] = w;
        }
    }

    __syncthreads();

    // ---- slot write: NO atomics, NO zero-init needed ----
    if (t < NC * 8) {                 // col = c*8 + k
        int c = t >> 3;
        int k = t & 7;
        float tot = 0.f;
        #pragma unroll
        for (int w = 0; w < NWAVE; ++w) tot += red[c][w][k];
        partial[(size_t)blk * SLOT + c * 8 + k] = tot;
    } else if (t < NC * 8 + 8) {      // col = 72 + k : class counts
        int k = t - NC * 8;
        float tot = 0.f;
        #pragma unroll
        for (int w = 0; w < NWAVE; ++w) tot += red_c[w][k];
        partial[(size_t)blk * SLOT + 72 + k] = tot;
    }
}

__global__ __launch_bounds__(1024)
void finalize_kernel(const float* __restrict__ partial,  // [GRID][SLOT]
                     float* __restrict__ out)
{
    __shared__ float tot[NB][SLOT];
    int t = threadIdx.x;

    // 640 threads: each reduces one (batch, col) over that batch's 192 blocks
    if (t < NB * SLOT) {
        int b = t / SLOT;
        int col = t % SLOT;
        const float* p = partial + (size_t)b * NCHUNK * SLOT + col;
        float s = 0.f;
        #pragma unroll 8
        for (int blk = 0; blk < NCHUNK; ++blk) s += p[(size_t)blk * SLOT];
        tot[b][col] = s;
    }
    __syncthreads();

    if (t < 64) {                    // one wave does the tiny math
        int b = t >> 3;
        int cls = t & 7;

        float cntv = tot[b][72 + cls];
        float denom = fmaxf(cntv, 1.0f);

        float pr[NC];
        float mx = -INFINITY;
        #pragma unroll
        for (int c = 0; c < NC; ++c) {
            pr[c] = tot[b][c * 8 + cls] / denom;
            mx = fmaxf(mx, pr[c]);
        }
        float se = 0.f;
        #pragma unroll
        for (int c = 0; c < NC; ++c) se += expf(pr[c] - mx);
        float lse = logf(se);

        float per = 0.f;
        #pragma unroll
        for (int c = 0; c < NC; ++c) {
            float tgt = (c == cls + 1) ? 0.9f : 0.0125f;
            per -= tgt * (pr[c] - mx - lse);
        }

        bool present = cntv > 0.f;
        float val = present ? per : 0.f;
        float np  = present ? 1.f : 0.f;
        #pragma unroll
        for (int off = 32; off > 0; off >>= 1) {
            val += __shfl_down(val, off, 64);
            np  += __shfl_down(np,  off, 64);
        }
        if (t == 0) out[0] = val / fmaxf(np, 1.f);
    }
}

extern "C" void kernel_launch(void* const* d_in, const int* in_sizes, int n_in,
                              void* d_out, int out_size, void* d_ws, size_t ws_size,
                              hipStream_t stream) {
    const int*   masks   = (const int*)d_in[0];
    const float* outputs = (const float*)d_in[1];
    float* partial = (float*)d_ws;   // GRID*SLOT floats = 480 KB, overwritten fully

    accum_kernel<<<GRID, BLOCK, 0, stream>>>(masks, outputs, partial);
    finalize_kernel<<<1, 1024, 0, stream>>>(partial, (float*)d_out);
}